// Round 9
// baseline (205.535 us; speedup 1.0000x reference)
//
#include <hip/hip_runtime.h>
#include <hip/hip_bf16.h>

#define BB 8
#define NN 2048
#define CC 256
#define DKK 64
#define DVV 256
#define COFF 60.0f

typedef __attribute__((ext_vector_type(8))) short bf16x8;
typedef __attribute__((ext_vector_type(4))) float f32x4;

#define MFMA16 __builtin_amdgcn_mfma_f32_16x16x32_bf16

static __device__ __forceinline__ unsigned short f2bf(float f) {
    unsigned int u = __float_as_uint(f);
    u += 0x7fffu + ((u >> 16) & 1u);
    return (unsigned short)(u >> 16);
}
static __device__ __forceinline__ float bf2f(unsigned short h) {
    return __uint_as_float(((unsigned int)h) << 16);
}

// async global->LDS, 16B per lane; LDS dest = wave-uniform base + lane*16
static __device__ __forceinline__ void g2l16(const unsigned short* g, unsigned short* l) {
    __builtin_amdgcn_global_load_lds(
        (const __attribute__((address_space(1))) void*)g,
        (__attribute__((address_space(3))) void*)l, 16, 0, 0);
}

// ---------------- kernel 0: split W -> swizzled bf16 images ---------------
// Wqk rows 0..63 = q, 64..127 = k (h and l planes); Wv rows 0..255 (h only).
// 256-elem rows, chunk c8=c>>3 stored at ((c8&24)|((c8^row)&7)).
__global__ void k_wt(const float* __restrict__ Wq, const float* __restrict__ Wk,
                     const float* __restrict__ Wv,
                     unsigned short* __restrict__ Wqkh_s, unsigned short* __restrict__ Wqkl_s,
                     unsigned short* __restrict__ Wvs) {
    int idx = blockIdx.x * 256 + threadIdx.x;
    if (idx >= 384 * 256) return;
    int d = idx >> 8, c = idx & 255;
    float w;
    if (d < 64)       w = Wq[d * 256 + c];
    else if (d < 128) w = Wk[(d - 64) * 256 + c];
    else              w = Wv[(d - 128) * 256 + c];
    unsigned short h = f2bf(w);
    int c8 = c >> 3;
    if (d < 128) {
        int row = d;
        int csw = (((c8 & 24) | ((c8 ^ row) & 7)) << 3) | (c & 7);
        Wqkh_s[row * 256 + csw] = h;
        Wqkl_s[row * 256 + csw] = f2bf(w - bf2f(h));
    } else {
        int row = d - 128;
        int csw = (((c8 & 24) | ((c8 ^ row) & 7)) << 3) | (c & 7);
        Wvs[row * 256 + csw] = h;
    }
}

// ---------------- kernel 1: fused projections, W staged in LDS ------------
// grid (256, 2): y=0 -> q/k role (3-pass split-bf16), y=1 -> v role (1-pass).
// 16 waves: wave (i = n-sub 0..3, j = d-group). x read fp32, split in regs.
__global__ __launch_bounds__(1024) void k_proj(
    const float* __restrict__ x,
    const unsigned short* __restrict__ Wqkh_s, const unsigned short* __restrict__ Wqkl_s,
    const unsigned short* __restrict__ Wvs,
    unsigned short* __restrict__ qh, unsigned short* __restrict__ ql,
    unsigned short* __restrict__ kh, unsigned short* __restrict__ kl,
    unsigned short* __restrict__ vT)
{
    __shared__ __align__(16) unsigned short Wlds[256 * 256];  // 128 KB
    int tid = threadIdx.x;
    int w = tid >> 6, lane = tid & 63;
    int t = lane & 15, qd = lane >> 4;
    int i = w >> 2, j = w & 3;
    int bn0 = blockIdx.x * 64;
    int role_qk = (blockIdx.y == 0);

    // one-time stage: 256 rows x 512B; 2 rows per wave-instr; 8 instrs/wave
    {
        int lr = lane >> 5, lc = (lane & 31) << 3;
        if (role_qk) {
            #pragma unroll
            for (int s = 0; s < 8; ++s) {
                int id = w * 8 + s;                 // 0..127
                int plane = id >> 6;
                int r0 = (id & 63) * 2;
                const unsigned short* src = (plane ? Wqkl_s : Wqkh_s) + (size_t)(r0 + lr) * 256 + lc;
                g2l16(src, &Wlds[0] + ((size_t)plane * 128 + r0) * 256);
            }
        } else {
            #pragma unroll
            for (int s = 0; s < 8; ++s) {
                int r0 = (w * 8 + s) * 2;
                g2l16(Wvs + (size_t)(r0 + lr) * 256 + lc, &Wlds[0] + (size_t)r0 * 256);
            }
        }
    }

    int bn = bn0 + i * 16 + t;
    int b = bn >> 11, n = bn & 2047;

    // x fp32 -> bf16 h/l fragments in registers (identical rounding to k_split)
    bf16x8 bh[8], bl[8];
    const float* xf = x + (size_t)bn * 256 + qd * 8;
    #pragma unroll
    for (int c = 0; c < 8; ++c) {
        float4 f0 = *(const float4*)(xf + c * 32);
        float4 f1 = *(const float4*)(xf + c * 32 + 4);
        float v[8] = {f0.x, f0.y, f0.z, f0.w, f1.x, f1.y, f1.z, f1.w};
        #pragma unroll
        for (int e = 0; e < 8; ++e) {
            unsigned short h = f2bf(v[e]);
            bh[c][e] = (short)h;
            bl[c][e] = (short)f2bf(v[e] - bf2f(h));
        }
    }

    __syncthreads();

    if (role_qk) {
        f32x4 acc[2];
        acc[0] = (f32x4){0.f, 0.f, 0.f, 0.f};
        acc[1] = (f32x4){0.f, 0.f, 0.f, 0.f};
        #pragma unroll
        for (int c = 0; c < 8; ++c) {
            #pragma unroll
            for (int k = 0; k < 2; ++k) {
                int d = j * 32 + k * 16 + t;        // d&7 == t&7
                int c8 = c * 4 + qd;
                int pos = d * 256 + ((((c8 & 24) | ((c8 ^ t) & 7))) << 3);
                bf16x8 ah = *(const bf16x8*)(&Wlds[pos]);
                bf16x8 al = *(const bf16x8*)(&Wlds[128 * 256 + pos]);
                acc[k] = MFMA16(ah, bh[c], acc[k], 0, 0, 0);
                acc[k] = MFMA16(ah, bl[c], acc[k], 0, 0, 0);
                acc[k] = MFMA16(al, bh[c], acc[k], 0, 0, 0);
            }
        }
        #pragma unroll
        for (int k = 0; k < 2; ++k) {
            ushort4 h4, l4;
            #pragma unroll
            for (int r = 0; r < 4; ++r) {
                unsigned short h = f2bf(acc[k][r]);
                ((unsigned short*)&h4)[r] = h;
                ((unsigned short*)&l4)[r] = f2bf(acc[k][r] - bf2f(h));
            }
            int dbase = j * 32 + k * 16 + qd * 4;   // 0..127
            int dd = dbase & 63;
            int sw = ((((dd >> 3) ^ bn) & 7) << 3) | (dd & 7);
            if (dbase < 64) {
                *(ushort4*)(qh + (size_t)bn * 64 + sw) = h4;
                *(ushort4*)(ql + (size_t)bn * 64 + sw) = l4;
            } else {
                *(ushort4*)(kh + (size_t)bn * 64 + sw) = h4;
                *(ushort4*)(kl + (size_t)bn * 64 + sw) = l4;
            }
        }
    } else {
        f32x4 acc[4];
        #pragma unroll
        for (int k = 0; k < 4; ++k) acc[k] = (f32x4){0.f, 0.f, 0.f, 0.f};
        #pragma unroll
        for (int c = 0; c < 8; ++c) {
            #pragma unroll
            for (int k = 0; k < 4; ++k) {
                int d = j * 64 + k * 16 + t;          // d&7 == t&7
                int c8 = c * 4 + qd;
                int pos = d * 256 + ((((c8 & 24) | ((c8 ^ t) & 7))) << 3);
                bf16x8 a = *(const bf16x8*)(&Wlds[pos]);
                acc[k] = MFMA16(a, bh[c], acc[k], 0, 0, 0);
            }
        }
        #pragma unroll
        for (int k = 0; k < 4; ++k) {
            #pragma unroll
            for (int r = 0; r < 4; ++r) {
                int dvd = j * 64 + k * 16 + qd * 4 + r;
                int nsw = (n & ~63) | ((((n >> 3) ^ dvd) & 7) << 3) | (n & 7);
                vT[((size_t)b * 256 + dvd) * 2048 + nsw] = f2bf(acc[k][r]);
            }
        }
    }
}

// ---------------- kernel 2: column sums, q-tile staged in LDS -------------
// grid (32 mt, 8 b), 16 waves: wave (i = m-sub, j = n-sub) of each 64x64 S-tile.
__global__ __launch_bounds__(1024) void k_colsum(
    const unsigned short* __restrict__ qh, const unsigned short* __restrict__ ql,
    const unsigned short* __restrict__ kh, const unsigned short* __restrict__ kl,
    float* __restrict__ cs)
{
    __shared__ __align__(16) unsigned short qbuf[2][2][64 * 64];  // [buf][h/l] 32 KB
    __shared__ float csbuf[4][64];
    int tid = threadIdx.x;
    int w = tid >> 6, lane = tid & 63;
    int t = lane & 15, qd = lane >> 4;
    int b = blockIdx.y, m0 = blockIdx.x * 64;
    int i = w >> 2, j = w & 3;

    int arow = m0 + i * 16 + t;
    int off0 = ((qd ^ (t & 7)) << 3);          // arow&7 == t&7
    const unsigned short* kbh = kh + ((size_t)b * 2048 + arow) * 64;
    const unsigned short* kbl = kl + ((size_t)b * 2048 + arow) * 64;
    bf16x8 ah0 = *(const bf16x8*)(kbh + off0);
    bf16x8 ah1 = *(const bf16x8*)(kbh + (off0 ^ 32));
    bf16x8 al0 = *(const bf16x8*)(kbl + off0);
    bf16x8 al1 = *(const bf16x8*)(kbl + (off0 ^ 32));

    int lr = lane >> 3, lc = (lane & 7) << 3;
    const unsigned short* qsrc = ((w < 8) ? qh : ql) +
        ((size_t)b * 2048 + (w & 7) * 8 + lr) * 64 + lc;
    unsigned short* qdst = &qbuf[0][w >> 3][(w & 7) * 8 * 64];

#define STAGEQ(bufi, itv) g2l16(qsrc + (size_t)(itv) * (64 * 64), qdst + (bufi) * (2 * 64 * 64))

    float ssum[4] = {0.f, 0.f, 0.f, 0.f};
    STAGEQ(0, 0);
    for (int it = 0; it < 32; ++it) {
        __syncthreads();                        // tile `it` staged; buf^1 free
        if (it + 1 < 32) STAGEQ((it + 1) & 1, it + 1);
        int cur = it & 1;
        int brow = j * 16 + t;                  // brow&7 == t&7
        const unsigned short* qrh = &qbuf[cur][0][brow * 64];
        const unsigned short* qrl = &qbuf[cur][1][brow * 64];
        bf16x8 bh0 = *(const bf16x8*)(qrh + off0);
        bf16x8 bh1 = *(const bf16x8*)(qrh + (off0 ^ 32));
        bf16x8 bl0 = *(const bf16x8*)(qrl + off0);
        bf16x8 bl1 = *(const bf16x8*)(qrl + (off0 ^ 32));
        f32x4 a0 = {0.f,0.f,0.f,0.f}, a1 = {0.f,0.f,0.f,0.f};
        a0 = MFMA16(ah0, bh0, a0, 0, 0, 0);
        a0 = MFMA16(ah1, bh1, a0, 0, 0, 0);
        a1 = MFMA16(ah0, bl0, a1, 0, 0, 0);
        a1 = MFMA16(ah1, bl1, a1, 0, 0, 0);
        a1 = MFMA16(al0, bh0, a1, 0, 0, 0);
        a1 = MFMA16(al1, bh1, a1, 0, 0, 0);
        #pragma unroll
        for (int r = 0; r < 4; ++r)
            ssum[r] += __expf((a0[r] + a1[r]) - COFF);
    }
#undef STAGEQ

    #pragma unroll
    for (int r = 0; r < 4; ++r) {
        float v = ssum[r];
        v += __shfl_xor(v, 1, 16);
        v += __shfl_xor(v, 2, 16);
        v += __shfl_xor(v, 4, 16);
        v += __shfl_xor(v, 8, 16);
        ssum[r] = v;
    }
    if (t == 0) {
        #pragma unroll
        for (int r = 0; r < 4; ++r) csbuf[j][i * 16 + qd * 4 + r] = ssum[r];
    }
    __syncthreads();
    if (tid < 64)
        cs[(size_t)b * 2048 + m0 + tid] =
            csbuf[0][tid] + csbuf[1][tid] + csbuf[2][tid] + csbuf[3][tid];
}

// ---------------- kernel 3: flash pass. 16 waves/block, grid (32,8). -------
// Prefetch STAGE issued FIRST after the top barrier so the vmcnt(0) drain at
// the second barrier overlaps the whole QK phase.
__global__ __launch_bounds__(1024) void k_attn(
    const unsigned short* __restrict__ qh, const unsigned short* __restrict__ ql,
    const unsigned short* __restrict__ kh, const unsigned short* __restrict__ kl,
    const unsigned short* __restrict__ vT, const float* __restrict__ cs,
    float* __restrict__ out)
{
    __shared__ __align__(16) unsigned short kbuf[2][128 * 64];
    __shared__ __align__(16) unsigned short vbuf[2][256 * 64];
    __shared__ __align__(16) unsigned short pP[64 * 72];
    __shared__ float cs_s[2048];
    __shared__ float rsbuf[4][64];

    int tid = threadIdx.x;
    int w = tid >> 6, lane = tid & 63;
    int t = lane & 15, qd = lane >> 4;
    int b = blockIdx.y;
    int n0 = blockIdx.x * 64;
    int i = w >> 2, j = w & 3;
    int i2 = w >> 3, j8 = w & 7;

    for (int u = tid; u < 2048; u += 1024) cs_s[u] = cs[(size_t)b * 2048 + u];

    // persistent q A-frags (qh/ql swizzled -> deswizzle like k-frags)
    int arow_a = n0 + i * 16 + t;
    int offq = ((qd ^ (t & 7)) << 3);          // arow_a&7 == t&7
    const unsigned short* qbh = qh + ((size_t)b * 2048 + arow_a) * 64;
    const unsigned short* qbl = ql + ((size_t)b * 2048 + arow_a) * 64;
    bf16x8 ah0 = *(const bf16x8*)(qbh + offq);
    bf16x8 ah1 = *(const bf16x8*)(qbh + (offq ^ 32));
    bf16x8 al0 = *(const bf16x8*)(qbl + offq);
    bf16x8 al1 = *(const bf16x8*)(qbl + (offq ^ 32));

    int lr = lane >> 3, lc = (lane & 7) << 3;
    const unsigned short* vsrc0 = vT + ((size_t)b * 256 + w * 16 + lr) * 2048 + lc;
    const unsigned short* vsrc1 = vT + ((size_t)b * 256 + w * 16 + 8 + lr) * 2048 + lc;
    const unsigned short* karr = (w < 8) ? kh : kl;
    const unsigned short* ksrc = karr + ((size_t)b * 2048 + (w & 7) * 8 + lr) * 64 + lc;
    unsigned short* vdst0 = &vbuf[0][0] + w * 1024;
    unsigned short* vdst1 = vdst0 + 512;
    unsigned short* kdst = &kbuf[0][0] + w * 512;

#define STAGE(bufi, m0s) do { \
        g2l16(vsrc0 + (m0s), vdst0 + (bufi) * 16384); \
        g2l16(vsrc1 + (m0s), vdst1 + (bufi) * 16384); \
        g2l16(ksrc + (size_t)(m0s) * 64, kdst + (bufi) * 8192); \
    } while (0)

    f32x4 accv[2][2];
    accv[0][0] = (f32x4){0.f,0.f,0.f,0.f}; accv[0][1] = (f32x4){0.f,0.f,0.f,0.f};
    accv[1][0] = (f32x4){0.f,0.f,0.f,0.f}; accv[1][1] = (f32x4){0.f,0.f,0.f,0.f};
    float rs[4] = {0.f, 0.f, 0.f, 0.f};

    STAGE(0, 0);

    for (int it = 0; it < 32; ++it) {
        __syncthreads();            // tile `it` staged; buf^1 fully consumed
        int cur = it & 1;
        int m0 = it * 64;
        // prefetch FIRST: its drain at the next barrier overlaps all of QK
        if (it + 1 < 32) STAGE(cur ^ 1, m0 + 64);
        {
            int mr = j * 16 + t;
            int off0 = ((qd ^ (t & 7)) << 3);
            const unsigned short* khrow = &kbuf[cur][mr * 64];
            const unsigned short* klrow = &kbuf[cur][(64 + mr) * 64];
            bf16x8 bh0 = *(const bf16x8*)(khrow + off0);
            bf16x8 bh1 = *(const bf16x8*)(khrow + (off0 ^ 32));
            bf16x8 bl0 = *(const bf16x8*)(klrow + off0);
            bf16x8 bl1 = *(const bf16x8*)(klrow + (off0 ^ 32));
            f32x4 s0 = {0.f,0.f,0.f,0.f}, s1 = {0.f,0.f,0.f,0.f};
            s0 = MFMA16(ah0, bh0, s0, 0, 0, 0);
            s0 = MFMA16(ah1, bh1, s0, 0, 0, 0);
            s1 = MFMA16(ah0, bl0, s1, 0, 0, 0);
            s1 = MFMA16(ah1, bl1, s1, 0, 0, 0);
            s1 = MFMA16(al0, bh0, s1, 0, 0, 0);
            s1 = MFMA16(al1, bh1, s1, 0, 0, 0);
            float rcs = 1.0f / cs_s[m0 + j * 16 + t];
            unsigned short* prow = pP + (size_t)(i * 16 + qd * 4) * 72 + j * 16 + t;
            #pragma unroll
            for (int r = 0; r < 4; ++r) {
                float p = __expf((s0[r] + s1[r]) - COFF) * rcs;
                rs[r] += p;
                prow[r * 72] = f2bf(p);
            }
        }
        __syncthreads();            // pP ready; prefetch drained (overlapped)
        {
            const unsigned short* vb = &vbuf[cur][0];
            #pragma unroll
            for (int c = 0; c < 2; ++c) {
                bf16x8 pa0 = *(const bf16x8*)(pP + (size_t)((2*i2 + 0) * 16 + t) * 72 + c * 32 + qd * 8);
                bf16x8 pa1 = *(const bf16x8*)(pP + (size_t)((2*i2 + 1) * 16 + t) * 72 + c * 32 + qd * 8);
                int ch = (((c * 4 + qd) ^ (t & 7)) << 3);
                bf16x8 vb0 = *(const bf16x8*)(vb + ((2*j8 + 0) * 16 + t) * 64 + ch);
                bf16x8 vb1 = *(const bf16x8*)(vb + ((2*j8 + 1) * 16 + t) * 64 + ch);
                accv[0][0] = MFMA16(pa0, vb0, accv[0][0], 0, 0, 0);
                accv[0][1] = MFMA16(pa0, vb1, accv[0][1], 0, 0, 0);
                accv[1][0] = MFMA16(pa1, vb0, accv[1][0], 0, 0, 0);
                accv[1][1] = MFMA16(pa1, vb1, accv[1][1], 0, 0, 0);
            }
        }
    }
#undef STAGE

    #pragma unroll
    for (int r = 0; r < 4; ++r) {
        float v = rs[r];
        v += __shfl_xor(v, 1, 16);
        v += __shfl_xor(v, 2, 16);
        v += __shfl_xor(v, 4, 16);
        v += __shfl_xor(v, 8, 16);
        rs[r] = v;
    }
    if (t == 0) {
        #pragma unroll
        for (int r = 0; r < 4; ++r) rsbuf[j][i * 16 + qd * 4 + r] = rs[r];
    }
    __syncthreads();

    #pragma unroll
    for (int s2 = 0; s2 < 2; ++s2) {
        #pragma unroll
        for (int r = 0; r < 4; ++r) {
            int nl = (2 * i2 + s2) * 16 + qd * 4 + r;
            float tot = rsbuf[0][nl] + rsbuf[1][nl] + rsbuf[2][nl] + rsbuf[3][nl];
            float sc = 1.0f / (1e-9f + tot);
            size_t orow = ((size_t)b * 2048 + n0 + nl) * 256;
            out[orow + (2 * j8 + 0) * 16 + t] = accv[s2][0][r] * sc;
            out[orow + (2 * j8 + 1) * 16 + t] = accv[s2][1][r] * sc;
        }
    }
}

extern "C" void kernel_launch(void* const* d_in, const int* in_sizes, int n_in,
                              void* d_out, int out_size, void* d_ws, size_t ws_size,
                              hipStream_t stream) {
    (void)in_sizes; (void)n_in; (void)out_size; (void)ws_size;
    const float* x  = (const float*)d_in[0];
    const float* Wq = (const float*)d_in[1];
    const float* Wk = (const float*)d_in[2];
    const float* Wv = (const float*)d_in[3];
    float* out = (float*)d_out;

    char* ws = (char*)d_ws;
    size_t off = 0;
    unsigned short* Wqkh_s = (unsigned short*)(ws + off); off += (size_t)128 * 256 * 2;
    unsigned short* Wqkl_s = (unsigned short*)(ws + off); off += (size_t)128 * 256 * 2;
    unsigned short* Wvs    = (unsigned short*)(ws + off); off += (size_t)256 * 256 * 2;
    unsigned short* qh = (unsigned short*)(ws + off); off += (size_t)BB * NN * DKK * 2;
    unsigned short* ql = (unsigned short*)(ws + off); off += (size_t)BB * NN * DKK * 2;
    unsigned short* kh = (unsigned short*)(ws + off); off += (size_t)BB * NN * DKK * 2;
    unsigned short* kl = (unsigned short*)(ws + off); off += (size_t)BB * NN * DKK * 2;
    unsigned short* vT = (unsigned short*)(ws + off); off += (size_t)BB * DVV * NN * 2;
    float* cs = (float*)(ws + off);                   off += (size_t)BB * NN * 4;

    hipLaunchKernelGGL(k_wt,     dim3(384),         dim3(256),  0, stream, Wq, Wk, Wv, Wqkh_s, Wqkl_s, Wvs);
    hipLaunchKernelGGL(k_proj,   dim3(256, 2),      dim3(1024), 0, stream, x, Wqkh_s, Wqkl_s, Wvs, qh, ql, kh, kl, vT);
    hipLaunchKernelGGL(k_colsum, dim3(NN / 64, BB), dim3(1024), 0, stream, qh, ql, kh, kl, cs);
    hipLaunchKernelGGL(k_attn,   dim3(NN / 64, BB), dim3(1024), 0, stream, qh, ql, kh, kl, vT, cs, out);
}

// Round 10
// 201.021 us; speedup vs baseline: 1.0225x; 1.0225x over previous
//
#include <hip/hip_runtime.h>
#include <hip/hip_bf16.h>

#define BB 8
#define NN 2048
#define CC 256
#define DKK 64
#define DVV 256
#define COFF 60.0f

typedef __attribute__((ext_vector_type(8))) short bf16x8;
typedef __attribute__((ext_vector_type(4))) float f32x4;

#define MFMA16 __builtin_amdgcn_mfma_f32_16x16x32_bf16

static __device__ __forceinline__ unsigned short f2bf(float f) {
    unsigned int u = __float_as_uint(f);
    u += 0x7fffu + ((u >> 16) & 1u);
    return (unsigned short)(u >> 16);
}
static __device__ __forceinline__ float bf2f(unsigned short h) {
    return __uint_as_float(((unsigned int)h) << 16);
}

// async global->LDS, 16B per lane; LDS dest = wave-uniform base + lane*16
static __device__ __forceinline__ void g2l16(const unsigned short* g, unsigned short* l) {
    __builtin_amdgcn_global_load_lds(
        (const __attribute__((address_space(1))) void*)g,
        (__attribute__((address_space(3))) void*)l, 16, 0, 0);
}

// ---------------- kernel 0: split W -> swizzled bf16 images ---------------
__global__ void k_wt(const float* __restrict__ Wq, const float* __restrict__ Wk,
                     const float* __restrict__ Wv,
                     unsigned short* __restrict__ Wqkh_s, unsigned short* __restrict__ Wqkl_s,
                     unsigned short* __restrict__ Wvs) {
    int idx = blockIdx.x * 256 + threadIdx.x;
    if (idx >= 384 * 256) return;
    int d = idx >> 8, c = idx & 255;
    float w;
    if (d < 64)       w = Wq[d * 256 + c];
    else if (d < 128) w = Wk[(d - 64) * 256 + c];
    else              w = Wv[(d - 128) * 256 + c];
    unsigned short h = f2bf(w);
    int c8 = c >> 3;
    if (d < 128) {
        int row = d;
        int csw = (((c8 & 24) | ((c8 ^ row) & 7)) << 3) | (c & 7);
        Wqkh_s[row * 256 + csw] = h;
        Wqkl_s[row * 256 + csw] = f2bf(w - bf2f(h));
    } else {
        int row = d - 128;
        int csw = (((c8 & 24) | ((c8 ^ row) & 7)) << 3) | (c & 7);
        Wvs[row * 256 + csw] = h;
    }
}

// ---------------- kernel 0b: split x into bf16 h/l ------------------------
__global__ __launch_bounds__(256) void k_split(
    const float* __restrict__ x,
    unsigned short* __restrict__ xh, unsigned short* __restrict__ xl) {
    int tid = blockIdx.x * 256 + threadIdx.x;
    const float4* xp = (const float4*)x + tid * 2;
    float4 a = xp[0], b = xp[1];
    float v[8] = {a.x, a.y, a.z, a.w, b.x, b.y, b.z, b.w};
    ushort4 h4[2], l4[2];
    #pragma unroll
    for (int i = 0; i < 8; ++i) {
        unsigned short h = f2bf(v[i]);
        ((unsigned short*)h4)[i] = h;
        ((unsigned short*)l4)[i] = f2bf(v[i] - bf2f(h));
    }
    ((ushort4*)xh)[tid * 2]     = h4[0];
    ((ushort4*)xh)[tid * 2 + 1] = h4[1];
    ((ushort4*)xl)[tid * 2]     = l4[0];
    ((ushort4*)xl)[tid * 2 + 1] = l4[1];
}

// ---------------- kernel 1a: v projection, W staged in LDS ----------------
__global__ __launch_bounds__(1024) void k_vproj(
    const unsigned short* __restrict__ xh, const unsigned short* __restrict__ Wvs,
    unsigned short* __restrict__ vT)
{
    __shared__ __align__(16) unsigned short Wlds[256 * 256];  // 128 KB
    int tid = threadIdx.x;
    int w = tid >> 6, lane = tid & 63;
    int t = lane & 15, qd = lane >> 4;
    int i = w >> 2, j = w & 3;
    int bn0 = blockIdx.x * 64;

    {
        int lr = lane >> 5, lc = (lane & 31) << 3;
        #pragma unroll
        for (int s = 0; s < 8; ++s) {
            int r0 = (w * 8 + s) * 2;
            g2l16(Wvs + (size_t)(r0 + lr) * 256 + lc, &Wlds[0] + (size_t)r0 * 256);
        }
    }

    int bn = bn0 + i * 16 + t;
    int b = bn >> 11, n = bn & 2047;
    bf16x8 bfr[8];
    const unsigned short* bp = xh + (size_t)bn * 256 + qd * 8;
    #pragma unroll
    for (int c = 0; c < 8; ++c) bfr[c] = *(const bf16x8*)(bp + c * 32);

    __syncthreads();

    f32x4 acc[4];
    #pragma unroll
    for (int k = 0; k < 4; ++k) acc[k] = (f32x4){0.f, 0.f, 0.f, 0.f};
    #pragma unroll
    for (int c = 0; c < 8; ++c) {
        #pragma unroll
        for (int k = 0; k < 4; ++k) {
            int d = j * 64 + k * 16 + t;          // d&7 == t&7
            int c8 = c * 4 + qd;
            int pos = d * 256 + ((((c8 & 24) | ((c8 ^ t) & 7))) << 3);
            bf16x8 a = *(const bf16x8*)(&Wlds[pos]);
            acc[k] = MFMA16(a, bfr[c], acc[k], 0, 0, 0);
        }
    }
    #pragma unroll
    for (int k = 0; k < 4; ++k) {
        #pragma unroll
        for (int r = 0; r < 4; ++r) {
            int dvd = j * 64 + k * 16 + qd * 4 + r;
            int nsw = (n & ~63) | ((((n >> 3) ^ dvd) & 7) << 3) | (n & 7);
            vT[((size_t)b * 256 + dvd) * 2048 + nsw] = f2bf(acc[k][r]);
        }
    }
}

// ---------------- kernel 1b: q/k projection, W(h+l) staged in LDS ---------
__global__ __launch_bounds__(1024) void k_qkproj(
    const unsigned short* __restrict__ xh, const unsigned short* __restrict__ xl,
    const unsigned short* __restrict__ Wqkh_s, const unsigned short* __restrict__ Wqkl_s,
    unsigned short* __restrict__ qh, unsigned short* __restrict__ ql,
    unsigned short* __restrict__ kh, unsigned short* __restrict__ kl)
{
    __shared__ __align__(16) unsigned short Wlds[2][128 * 256];  // 128 KB
    int tid = threadIdx.x;
    int w = tid >> 6, lane = tid & 63;
    int t = lane & 15, qd = lane >> 4;
    int i = w >> 2, j = w & 3;
    int bn0 = blockIdx.x * 64;

    {
        int lr = lane >> 5, lc = (lane & 31) << 3;
        #pragma unroll
        for (int s = 0; s < 8; ++s) {
            int id = w * 8 + s;
            int plane = id >> 6;
            int r0 = (id & 63) * 2;
            const unsigned short* src = (plane ? Wqkl_s : Wqkh_s) + (size_t)(r0 + lr) * 256 + lc;
            g2l16(src, &Wlds[plane][0] + (size_t)r0 * 256);
        }
    }

    int bn = bn0 + i * 16 + t;
    bf16x8 bh[8], bl[8];
    const unsigned short* bph = xh + (size_t)bn * 256 + qd * 8;
    const unsigned short* bpl = xl + (size_t)bn * 256 + qd * 8;
    #pragma unroll
    for (int c = 0; c < 8; ++c) {
        bh[c] = *(const bf16x8*)(bph + c * 32);
        bl[c] = *(const bf16x8*)(bpl + c * 32);
    }

    __syncthreads();

    f32x4 acc[2];
    acc[0] = (f32x4){0.f, 0.f, 0.f, 0.f};
    acc[1] = (f32x4){0.f, 0.f, 0.f, 0.f};
    #pragma unroll
    for (int c = 0; c < 8; ++c) {
        #pragma unroll
        for (int k = 0; k < 2; ++k) {
            int d = j * 32 + k * 16 + t;
            int c8 = c * 4 + qd;
            int pos = d * 256 + ((((c8 & 24) | ((c8 ^ t) & 7))) << 3);
            bf16x8 ah = *(const bf16x8*)(&Wlds[0][pos]);
            bf16x8 al = *(const bf16x8*)(&Wlds[1][pos]);
            acc[k] = MFMA16(ah, bh[c], acc[k], 0, 0, 0);
            acc[k] = MFMA16(ah, bl[c], acc[k], 0, 0, 0);
            acc[k] = MFMA16(al, bh[c], acc[k], 0, 0, 0);
        }
    }
    #pragma unroll
    for (int k = 0; k < 2; ++k) {
        ushort4 h4, l4;
        #pragma unroll
        for (int r = 0; r < 4; ++r) {
            unsigned short h = f2bf(acc[k][r]);
            ((unsigned short*)&h4)[r] = h;
            ((unsigned short*)&l4)[r] = f2bf(acc[k][r] - bf2f(h));
        }
        int dbase = j * 32 + k * 16 + qd * 4;
        int dd = dbase & 63;
        int sw = ((((dd >> 3) ^ bn) & 7) << 3) | (dd & 7);
        if (dbase < 64) {
            *(ushort4*)(qh + (size_t)bn * 64 + sw) = h4;
            *(ushort4*)(ql + (size_t)bn * 64 + sw) = l4;
        } else {
            *(ushort4*)(kh + (size_t)bn * 64 + sw) = h4;
            *(ushort4*)(kl + (size_t)bn * 64 + sw) = l4;
        }
    }
}

// ---------------- kernel 2: column sums, q-tile staged in LDS -------------
__global__ __launch_bounds__(1024) void k_colsum(
    const unsigned short* __restrict__ qh, const unsigned short* __restrict__ ql,
    const unsigned short* __restrict__ kh, const unsigned short* __restrict__ kl,
    float* __restrict__ cs)
{
    __shared__ __align__(16) unsigned short qbuf[2][2][64 * 64];
    __shared__ float csbuf[4][64];
    int tid = threadIdx.x;
    int w = tid >> 6, lane = tid & 63;
    int t = lane & 15, qd = lane >> 4;
    int b = blockIdx.y, m0 = blockIdx.x * 64;
    int i = w >> 2, j = w & 3;

    int arow = m0 + i * 16 + t;
    int off0 = ((qd ^ (t & 7)) << 3);
    const unsigned short* kbh = kh + ((size_t)b * 2048 + arow) * 64;
    const unsigned short* kbl = kl + ((size_t)b * 2048 + arow) * 64;
    bf16x8 ah0 = *(const bf16x8*)(kbh + off0);
    bf16x8 ah1 = *(const bf16x8*)(kbh + (off0 ^ 32));
    bf16x8 al0 = *(const bf16x8*)(kbl + off0);
    bf16x8 al1 = *(const bf16x8*)(kbl + (off0 ^ 32));

    int lr = lane >> 3, lc = (lane & 7) << 3;
    const unsigned short* qsrc = ((w < 8) ? qh : ql) +
        ((size_t)b * 2048 + (w & 7) * 8 + lr) * 64 + lc;
    unsigned short* qdst = &qbuf[0][w >> 3][(w & 7) * 8 * 64];

#define STAGEQ(bufi, itv) g2l16(qsrc + (size_t)(itv) * (64 * 64), qdst + (bufi) * (2 * 64 * 64))

    float ssum[4] = {0.f, 0.f, 0.f, 0.f};
    STAGEQ(0, 0);
    for (int it = 0; it < 32; ++it) {
        __syncthreads();
        if (it + 1 < 32) STAGEQ((it + 1) & 1, it + 1);
        int cur = it & 1;
        int brow = j * 16 + t;
        const unsigned short* qrh = &qbuf[cur][0][brow * 64];
        const unsigned short* qrl = &qbuf[cur][1][brow * 64];
        bf16x8 bh0 = *(const bf16x8*)(qrh + off0);
        bf16x8 bh1 = *(const bf16x8*)(qrh + (off0 ^ 32));
        bf16x8 bl0 = *(const bf16x8*)(qrl + off0);
        bf16x8 bl1 = *(const bf16x8*)(qrl + (off0 ^ 32));
        f32x4 a0 = {0.f,0.f,0.f,0.f}, a1 = {0.f,0.f,0.f,0.f};
        a0 = MFMA16(ah0, bh0, a0, 0, 0, 0);
        a0 = MFMA16(ah1, bh1, a0, 0, 0, 0);
        a1 = MFMA16(ah0, bl0, a1, 0, 0, 0);
        a1 = MFMA16(ah1, bl1, a1, 0, 0, 0);
        a1 = MFMA16(al0, bh0, a1, 0, 0, 0);
        a1 = MFMA16(al1, bh1, a1, 0, 0, 0);
        #pragma unroll
        for (int r = 0; r < 4; ++r)
            ssum[r] += __expf((a0[r] + a1[r]) - COFF);
    }
#undef STAGEQ

    #pragma unroll
    for (int r = 0; r < 4; ++r) {
        float v = ssum[r];
        v += __shfl_xor(v, 1, 16);
        v += __shfl_xor(v, 2, 16);
        v += __shfl_xor(v, 4, 16);
        v += __shfl_xor(v, 8, 16);
        ssum[r] = v;
    }
    if (t == 0) {
        #pragma unroll
        for (int r = 0; r < 4; ++r) csbuf[j][i * 16 + qd * 4 + r] = ssum[r];
    }
    __syncthreads();
    if (tid < 64)
        cs[(size_t)b * 2048 + m0 + tid] =
            csbuf[0][tid] + csbuf[1][tid] + csbuf[2][tid] + csbuf[3][tid];
}

// ---------------- kernel 3: flash pass, 8 waves, 32-row n-tile ------------
// grid (64, 8) = 512 blocks, 512 thr -> 2-3 independent barrier domains/CU.
// v read direct from L2 (no vbuf); kbuf (k h+l) double-buffered, 45 KB LDS.
// QK role: wave (i = n-sub 0..1, j = m-sub 0..3); PV: (i2 = n-sub, j4 = d-64grp).
__global__ __launch_bounds__(512) void k_attn(
    const unsigned short* __restrict__ qh, const unsigned short* __restrict__ ql,
    const unsigned short* __restrict__ kh, const unsigned short* __restrict__ kl,
    const unsigned short* __restrict__ vT, const float* __restrict__ cs,
    float* __restrict__ out)
{
    __shared__ __align__(16) unsigned short kbuf[2][128 * 64];  // 32 KB
    __shared__ __align__(16) unsigned short pP[32 * 72];        // 4.5 KB
    __shared__ float cs_s[2048];                                // 8 KB
    __shared__ float rsbuf[4][32];

    int tid = threadIdx.x;
    int w = tid >> 6, lane = tid & 63;
    int t = lane & 15, qd = lane >> 4;
    int b = blockIdx.y;
    int n0 = blockIdx.x * 32;
    int i = w >> 2, j = w & 3;       // QK roles
    int i2 = w & 1, j4 = w >> 1;     // PV roles

    for (int u = tid; u < 2048; u += 512) cs_s[u] = cs[(size_t)b * 2048 + u];

    // persistent q A-frags (qh/ql row-swizzled -> deswizzle)
    int arow_a = n0 + i * 16 + t;
    int offq = ((qd ^ (t & 7)) << 3);
    const unsigned short* qbh = qh + ((size_t)b * 2048 + arow_a) * 64;
    const unsigned short* qbl = ql + ((size_t)b * 2048 + arow_a) * 64;
    bf16x8 ah0 = *(const bf16x8*)(qbh + offq);
    bf16x8 ah1 = *(const bf16x8*)(qbh + (offq ^ 32));
    bf16x8 al0 = *(const bf16x8*)(qbl + offq);
    bf16x8 al1 = *(const bf16x8*)(qbl + (offq ^ 32));

    // k staging: wave w stages 2 chunks; id = w*2+s: plane id>>3, rows (id&7)*8..+8
    int lr = lane >> 3, lc = (lane & 7) << 3;
    const unsigned short* ksrc0 = ((w * 2 + 0) >> 3 ? kl : kh) +
        ((size_t)b * 2048 + ((w * 2 + 0) & 7) * 8 + lr) * 64 + lc;
    const unsigned short* ksrc1 = ((w * 2 + 1) >> 3 ? kl : kh) +
        ((size_t)b * 2048 + ((w * 2 + 1) & 7) * 8 + lr) * 64 + lc;
    unsigned short* kdst0 = &kbuf[0][0] + ((((w * 2 + 0) >> 3) * 64 + ((w * 2 + 0) & 7) * 8) * 64);
    unsigned short* kdst1 = &kbuf[0][0] + ((((w * 2 + 1) >> 3) * 64 + ((w * 2 + 1) & 7) * 8) * 64);

#define STAGE(bufi, m0s) do { \
        g2l16(ksrc0 + (size_t)(m0s) * 64, kdst0 + (bufi) * 8192); \
        g2l16(ksrc1 + (size_t)(m0s) * 64, kdst1 + (bufi) * 8192); \
    } while (0)

    f32x4 acc[4];
    #pragma unroll
    for (int ds = 0; ds < 4; ++ds) acc[ds] = (f32x4){0.f, 0.f, 0.f, 0.f};
    float rs[4] = {0.f, 0.f, 0.f, 0.f};

    STAGE(0, 0);

    for (int it = 0; it < 32; ++it) {
        __syncthreads();            // k tile `it` staged; pP of it-1 consumed
        int cur = it & 1;
        int m0 = it * 64;
        // ---- QK: one 16x16 S-tile per wave ----
        {
            int mr = j * 16 + t;
            int off0 = ((qd ^ (t & 7)) << 3);
            const unsigned short* khrow = &kbuf[cur][mr * 64];
            const unsigned short* klrow = &kbuf[cur][(64 + mr) * 64];
            bf16x8 bh0 = *(const bf16x8*)(khrow + off0);
            bf16x8 bh1 = *(const bf16x8*)(khrow + (off0 ^ 32));
            bf16x8 bl0 = *(const bf16x8*)(klrow + off0);
            bf16x8 bl1 = *(const bf16x8*)(klrow + (off0 ^ 32));
            f32x4 s0 = {0.f,0.f,0.f,0.f}, s1 = {0.f,0.f,0.f,0.f};
            s0 = MFMA16(ah0, bh0, s0, 0, 0, 0);
            s0 = MFMA16(ah1, bh1, s0, 0, 0, 0);
            s1 = MFMA16(ah0, bl0, s1, 0, 0, 0);
            s1 = MFMA16(ah1, bl1, s1, 0, 0, 0);
            s1 = MFMA16(al0, bh0, s1, 0, 0, 0);
            s1 = MFMA16(al1, bh1, s1, 0, 0, 0);
            float rcs = 1.0f / cs_s[m0 + j * 16 + t];
            unsigned short* prow = pP + (size_t)(i * 16 + qd * 4) * 72 + j * 16 + t;
            #pragma unroll
            for (int r = 0; r < 4; ++r) {
                float p = __expf((s0[r] + s1[r]) - COFF) * rcs;
                rs[r] += p;
                prow[r * 72] = f2bf(p);
            }
        }
        if (it + 1 < 32) STAGE(cur ^ 1, m0 + 64);   // R8-proven position
        __syncthreads();            // pP ready
        // ---- PV: 16n x 64d per wave over 64 m; v direct from global ----
        #pragma unroll
        for (int c = 0; c < 2; ++c) {
            bf16x8 pa = *(const bf16x8*)(pP + (size_t)(i2 * 16 + t) * 72 + c * 32 + qd * 8);
            int ch = (((c * 4 + qd) ^ (t & 7)) << 3);
            bf16x8 vbf[4];
            #pragma unroll
            for (int ds = 0; ds < 4; ++ds) {
                int vrow = j4 * 64 + ds * 16 + t;
                vbf[ds] = *(const bf16x8*)(vT + ((size_t)b * 256 + vrow) * 2048 + m0 + ch);
            }
            #pragma unroll
            for (int ds = 0; ds < 4; ++ds)
                acc[ds] = MFMA16(pa, vbf[ds], acc[ds], 0, 0, 0);
        }
    }
#undef STAGE

    #pragma unroll
    for (int r = 0; r < 4; ++r) {
        float v = rs[r];
        v += __shfl_xor(v, 1, 16);
        v += __shfl_xor(v, 2, 16);
        v += __shfl_xor(v, 4, 16);
        v += __shfl_xor(v, 8, 16);
        rs[r] = v;
    }
    if (t == 0) {
        #pragma unroll
        for (int r = 0; r < 4; ++r) rsbuf[j][i * 16 + qd * 4 + r] = rs[r];
    }
    __syncthreads();

    #pragma unroll
    for (int r = 0; r < 4; ++r) {
        int nl = i2 * 16 + qd * 4 + r;
        float tot = rsbuf[0][nl] + rsbuf[1][nl] + rsbuf[2][nl] + rsbuf[3][nl];
        float sc = 1.0f / (1e-9f + tot);
        size_t orow = ((size_t)b * 2048 + n0 + nl) * 256;
        #pragma unroll
        for (int ds = 0; ds < 4; ++ds)
            out[orow + j4 * 64 + ds * 16 + t] = acc[ds][r] * sc;
    }
}

extern "C" void kernel_launch(void* const* d_in, const int* in_sizes, int n_in,
                              void* d_out, int out_size, void* d_ws, size_t ws_size,
                              hipStream_t stream) {
    (void)in_sizes; (void)n_in; (void)out_size; (void)ws_size;
    const float* x  = (const float*)d_in[0];
    const float* Wq = (const float*)d_in[1];
    const float* Wk = (const float*)d_in[2];
    const float* Wv = (const float*)d_in[3];
    float* out = (float*)d_out;

    char* ws = (char*)d_ws;
    size_t off = 0;
    unsigned short* Wqkh_s = (unsigned short*)(ws + off); off += (size_t)128 * 256 * 2;
    unsigned short* Wqkl_s = (unsigned short*)(ws + off); off += (size_t)128 * 256 * 2;
    unsigned short* Wvs    = (unsigned short*)(ws + off); off += (size_t)256 * 256 * 2;
    unsigned short* xh = (unsigned short*)(ws + off); off += (size_t)BB * NN * CC * 2;
    unsigned short* xl = (unsigned short*)(ws + off); off += (size_t)BB * NN * CC * 2;
    unsigned short* qh = (unsigned short*)(ws + off); off += (size_t)BB * NN * DKK * 2;
    unsigned short* ql = (unsigned short*)(ws + off); off += (size_t)BB * NN * DKK * 2;
    unsigned short* kh = (unsigned short*)(ws + off); off += (size_t)BB * NN * DKK * 2;
    unsigned short* kl = (unsigned short*)(ws + off); off += (size_t)BB * NN * DKK * 2;
    unsigned short* vT = (unsigned short*)(ws + off); off += (size_t)BB * DVV * NN * 2;
    float* cs = (float*)(ws + off);                   off += (size_t)BB * NN * 4;

    hipLaunchKernelGGL(k_wt,     dim3(384),         dim3(256),  0, stream, Wq, Wk, Wv, Wqkh_s, Wqkl_s, Wvs);
    hipLaunchKernelGGL(k_split,  dim3(2048),        dim3(256),  0, stream, x, xh, xl);
    hipLaunchKernelGGL(k_vproj,  dim3(256),         dim3(1024), 0, stream, xh, Wvs, vT);
    hipLaunchKernelGGL(k_qkproj, dim3(256),         dim3(1024), 0, stream, xh, xl, Wqkh_s, Wqkl_s, qh, ql, kh, kl);
    hipLaunchKernelGGL(k_colsum, dim3(NN / 64, BB), dim3(1024), 0, stream, qh, ql, kh, kl, cs);
    hipLaunchKernelGGL(k_attn,   dim3(NN / 32, BB), dim3(512),  0, stream, qh, ql, kh, kl, vT, cs, out);
}